// Round 8
// baseline (192.875 us; speedup 1.0000x reference)
//
#include <hip/hip_runtime.h>

// Workspace layout: float region + int region (ints start at (int*)wsf + 64)
#define WSF_W1Q  0      // 36 floats: s1*lvl (exact)
#define WSF_SF2  36     // 2*sf
#define WSI_W2P  0      // 36 ints: conv2 packed ternary i8x4 (ic in bytes), [oc][tap]
#define WSI_L1   36     // conv2 integer thresholds on L = sum(lvl_in * w), lvl in {0..3}
#define WSI_L3   37
#define WSI_L5   38
#define WSI_WFP  40     // 49*12 ints: FC packed ternary i8x4, [pix][o] pitch 12; byte b = wf[o][b*49+pix]

#define TOL2 4e-5f      // rescue band half-width in f-units (f = mx/2)

typedef float v2f __attribute__((ext_vector_type(2)));

__device__ __forceinline__ int dot4(int a, int b, int c) {
    return __builtin_amdgcn_sdot4(a, b, c, false);
}
__device__ __forceinline__ int pk_add16(int a, int b) {
    int r;
    asm("v_pk_add_i16 %0, %1, %2" : "=v"(r) : "v"(a), "v"(b));
    return r;
}
// packed 2xfp32 FMA, weight pair in SGPRs (uniform): src0 is the 1 allowed SGPR
__device__ __forceinline__ v2f pk_fma_sv(v2f ws, v2f d, v2f acc) {
    v2f r;
    asm("v_pk_fma_f32 %0, %1, %2, %3" : "=v"(r) : "s"(ws), "v"(d), "v"(acc));
    return r;
}

// wave-local LDS drain (no cross-wave rendezvous needed: zero inter-wave sharing)
#define LDS_FENCE() asm volatile("s_waitcnt lgkmcnt(0)" ::: "memory")

// ---------------------------------------------------------------------------
// Pre-kernel: 2-bit weight quant (fp64 decisions) + integer packing. 256 thr.
// ---------------------------------------------------------------------------
__global__ void qweights_kernel(const float* __restrict__ w1,
                                const float* __restrict__ w2,
                                const float* __restrict__ wf,
                                float* __restrict__ wsf) {
    int* wsi = (int*)wsf + 64;
    __shared__ float red[256];
    const int tid = threadIdx.x;

    float m = 0.f;
    if (tid < 36) m = fabsf(w1[tid]);
    red[tid] = m; __syncthreads();
    for (int s = 128; s > 0; s >>= 1) { if (tid < s) red[tid] = fmaxf(red[tid], red[tid + s]); __syncthreads(); }
    const float s1 = red[0]; __syncthreads();

    m = 0.f;
    if (tid < 144) m = fabsf(w2[tid]);
    red[tid] = m; __syncthreads();
    for (int s = 128; s > 0; s >>= 1) { if (tid < s) red[tid] = fmaxf(red[tid], red[tid + s]); __syncthreads(); }
    const float s2 = red[0]; __syncthreads();

    m = 0.f;
    for (int i = tid; i < 1960; i += 256) m = fmaxf(m, fabsf(wf[i]));
    red[tid] = m; __syncthreads();
    for (int s = 128; s > 0; s >>= 1) { if (tid < s) red[tid] = fmaxf(red[tid], red[tid + s]); __syncthreads(); }
    const float sf = red[0];

    if (tid < 36) {
        double l = rint((double)w1[tid] / (double)s1);
        l = fmin(fmax(l, -1.0), 1.0);
        wsf[WSF_W1Q + tid] = (float)(l * (double)s1);
    }
    if (tid >= 64 && tid < 100) {
        int u = tid - 64;
        int oc = u / 9, tap = u % 9;
        int dy = tap / 3, dx = tap % 3;
        int v = 0;
        for (int ic = 0; ic < 4; ++ic) {
            double l = rint((double)w2[((oc * 4 + ic) * 3 + dy) * 3 + dx] / (double)s2);
            l = fmin(fmax(l, -1.0), 1.0);
            v |= ((int)l & 0xFF) << (8 * ic);
        }
        wsi[WSI_W2P + u] = v;
    }
    // FC pack [pix][o]: byte b = lvl(wf[o*196 + b*49 + pix]) -- matches h4 packing
    for (int u = tid; u < 49 * 12; u += 256) {
        int pix = u / 12, o = u - 12 * pix;
        int v = 0;
        if (o < 10) {
            for (int b = 0; b < 4; ++b) {
                double l = rint((double)wf[o * 196 + b * 49 + pix] / (double)sf);
                l = fmin(fmax(l, -1.0), 1.0);
                v |= ((int)l & 0xFF) << (8 * b);
            }
        }
        wsi[WSI_WFP + u] = v;
    }
    // conv2 thresholds via wave-0 ballot: pre-act = 2*s2*L, L in [0,108]
    if (tid < 64) {
        const int lane = tid;
        double xa = 2.0 * (double)s2 * (double)lane;
        double xb = 2.0 * (double)s2 * (double)(lane + 64);
        double la = rint(fmin(fmax(xa, 0.0), 6.0) * 0.5);
        double lb = rint(fmin(fmax(xb, 0.0), 6.0) * 0.5);
        unsigned long long b1a = __ballot(la >= 1.0), b1b = __ballot(lb >= 1.0);
        unsigned long long b3a = __ballot(la >= 2.0), b3b = __ballot(lb >= 2.0);
        unsigned long long b5a = __ballot(la >= 3.0), b5b = __ballot(lb >= 3.0);
        if (lane == 0) {
            int L1 = b1a ? __ffsll(b1a) - 1 : (b1b ? 64 + __ffsll(b1b) - 1 : 4096);
            int L3 = b3a ? __ffsll(b3a) - 1 : (b3b ? 64 + __ffsll(b3b) - 1 : 4096);
            int L5 = b5a ? __ffsll(b5a) - 1 : (b5b ? 64 + __ffsll(b5b) - 1 : 4096);
            wsi[WSI_L1] = L1; wsi[WSI_L3] = L3; wsi[WSI_L5] = L5;
            wsf[WSF_SF2] = 2.0f * sf;
        }
    }
}

// ---------------------------------------------------------------------------
// Fused net: one wave per image, 4 waves/block, no __syncthreads.
// Ternary zero-weight work is skipped via wave-uniform branches (scalar pipe);
// skipping is semantically a no-op (fma/dot4 with 0 weight), so correctness
// is identical whether or not the compiler keeps the branches.
// ---------------------------------------------------------------------------
#define WAVES 4
#define P_IN 30
#define P_P1 18

__global__ __launch_bounds__(256, 8)
void fused_net_kernel(const float* __restrict__ x,
                      const float* __restrict__ wsf,
                      float* __restrict__ out, int B) {
    const int* wsi = (const int*)wsf + 64;

    __shared__ __align__(16) float s_in[WAVES][900];        // 30x30 padded
    __shared__ __align__(16) int   s_p1[WAVES][16 * P_P1];  // packed lvl{0..3} x4 ic

    const int tid  = threadIdx.x;
    const int wave = tid >> 6;
    const int lane = tid & 63;
    const int img  = blockIdx.x * WAVES + wave;
    const bool act = (img < B);

    float* in_p = s_in[wave];
    int*   p1i  = s_p1[wave];
    const float* w1 = wsf + WSF_W1Q;

    // ---- phase 0a: zero exactly the READ-SET border frames ----
    if (lane < 30) { in_p[lane] = 0.f; in_p[29 * 30 + lane] = 0.f; }
    if (lane < 28) { in_p[(lane + 1) * 30] = 0.f; in_p[(lane + 1) * 30 + 29] = 0.f; }
    // p1i read set rows 0..15 x cols 0..15; interior rows/cols 1..14 written.
    if (lane < 60) {
        int bi;
        if (lane < 16)      bi = lane;                       // row 0, cols 0..15
        else if (lane < 32) bi = 15 * P_P1 + (lane - 16);    // row 15, cols 0..15
        else if (lane < 46) bi = (lane - 31) * P_P1;         // rows 1..14, col 0
        else                bi = (lane - 45) * P_P1 + 15;    // rows 1..14, col 15
        p1i[bi] = 0;
    }

    // ---- phase 0b: load 28x28 input into padded interior ----
    if (act) {
        const float4* xv = (const float4*)(x + (size_t)img * 784);
        for (int t = lane; t < 196; t += 64) {
            float4 v = xv[t];
            int row = t / 7;
            int c   = (t - row * 7) * 4;
            float* dst = in_p + (row + 1) * P_IN + c + 1;
            dst[0] = v.x; dst[1] = v.y; dst[2] = v.z; dst[3] = v.w;
        }
    }
    LDS_FENCE();

    // ---- phase 1: conv1 via v_pk_fma_f32 with ternary skip (+fp64 rescue) ----
    if (act) {
        #pragma unroll
        for (int it = 0; it < 3; ++it) {
            const int t = lane + (it << 6);            // < 192
            const int i = t / 14, j = t - i * 14;
            const float* base = in_p + (2 * i) * P_IN + 2 * j;
            v2f A[4], S[4], Bp[4];                      // cols {0,1},{1,2},{2,3}
            #pragma unroll
            for (int r = 0; r < 4; ++r) {
                const float* rp = base + r * P_IN;
                A[r]  = *(const v2f*)rp;
                Bp[r] = *(const v2f*)(rp + 2);
                v2f s; s.x = rp[1]; s.y = rp[2];
                S[r] = s;
            }
            float rr[4];
            float dmax = 0.f;
            #pragma unroll
            for (int oc = 0; oc < 4; ++oc) {
                const float* w9 = w1 + oc * 9;
                v2f acc01 = {0.f, 0.f}, acc23 = {0.f, 0.f};
                #pragma unroll
                for (int r = 0; r < 3; ++r) {
                    float wa = w9[r * 3], wb = w9[r * 3 + 1], wc = w9[r * 3 + 2];
                    if (wa != 0.f) {                    // uniform skip: no-op if kept
                        v2f wav = {wa, wa};
                        acc01 = pk_fma_sv(wav, A[r],      acc01);
                        acc23 = pk_fma_sv(wav, A[r + 1],  acc23);
                    }
                    if (wb != 0.f) {
                        v2f wbv = {wb, wb};
                        acc01 = pk_fma_sv(wbv, S[r],      acc01);
                        acc23 = pk_fma_sv(wbv, S[r + 1],  acc23);
                    }
                    if (wc != 0.f) {
                        v2f wcv = {wc, wc};
                        acc01 = pk_fma_sv(wcv, Bp[r],     acc01);
                        acc23 = pk_fma_sv(wcv, Bp[r + 1], acc23);
                    }
                }
                float mx = fmaxf(fmaxf(acc01.x, acc01.y), fmaxf(acc23.x, acc23.y));
                float cc = fminf(fmaxf(0.5f * mx, 0.f), 3.f);
                float rv = rintf(cc);
                rr[oc] = rv;
                dmax = fmaxf(dmax, fabsf(cc - rv));
            }
            if (dmax > 0.5f - TOL2) {                  // rare fp64 rescue
                double dd[4][4];
                #pragma unroll
                for (int r = 0; r < 4; ++r) {
                    dd[r][0] = (double)A[r].x; dd[r][1] = (double)A[r].y;
                    dd[r][2] = (double)Bp[r].x; dd[r][3] = (double)Bp[r].y;
                }
                #pragma unroll
                for (int oc = 0; oc < 4; ++oc) {
                    double a00 = 0, a01 = 0, a10 = 0, a11 = 0;
                    #pragma unroll
                    for (int r = 0; r < 3; ++r)
                        #pragma unroll
                        for (int c = 0; c < 3; ++c) {
                            double wv = (double)w1[oc * 9 + r * 3 + c];
                            a00 = fma(wv, dd[r][c],         a00);
                            a01 = fma(wv, dd[r][c + 1],     a01);
                            a10 = fma(wv, dd[r + 1][c],     a10);
                            a11 = fma(wv, dd[r + 1][c + 1], a11);
                        }
                    double mx = fmax(fmax(a00, a01), fmax(a10, a11));
                    rr[oc] = (float)rint(fmin(fmax(0.5 * mx, 0.0), 3.0));
                }
            }
            p1i[(i + 1) * P_P1 + (j + 1)] =
                (int)rr[0] | ((int)rr[1] << 8) | ((int)rr[2] << 16) | ((int)rr[3] << 24);
        }
        // tail: pixels 192..195, oc-split over lanes 0..15
        if (lane < 16) {
            const int px = 192 + (lane >> 2), oc = lane & 3;
            const int i = 13, j = px - 182;            // j in 10..13
            const float* base = in_p + (2 * i) * P_IN + 2 * j;
            float d[4][4];
            #pragma unroll
            for (int r = 0; r < 4; ++r) {
                float2 a = *(const float2*)(base + r * P_IN);
                float2 b = *(const float2*)(base + r * P_IN + 2);
                d[r][0] = a.x; d[r][1] = a.y; d[r][2] = b.x; d[r][3] = b.y;
            }
            const float* w9 = w1 + oc * 9;
            float a00 = 0.f, a01 = 0.f, a10 = 0.f, a11 = 0.f;
            #pragma unroll
            for (int r = 0; r < 3; ++r)
                #pragma unroll
                for (int c = 0; c < 3; ++c) {
                    float wv = w9[r * 3 + c];
                    a00 = fmaf(wv, d[r][c],         a00);
                    a01 = fmaf(wv, d[r][c + 1],     a01);
                    a10 = fmaf(wv, d[r + 1][c],     a10);
                    a11 = fmaf(wv, d[r + 1][c + 1], a11);
                }
            float mx = fmaxf(fmaxf(a00, a01), fmaxf(a10, a11));
            float cc = fminf(fmaxf(0.5f * mx, 0.f), 3.f);
            float rv = rintf(cc);
            if (fabsf(cc - rv) > 0.5f - TOL2) {
                double dd00 = 0, dd01 = 0, dd10 = 0, dd11 = 0;
                #pragma unroll
                for (int r = 0; r < 3; ++r)
                    #pragma unroll
                    for (int c = 0; c < 3; ++c) {
                        double wv = (double)w9[r * 3 + c];
                        dd00 = fma(wv, (double)d[r][c],         dd00);
                        dd01 = fma(wv, (double)d[r][c + 1],     dd01);
                        dd10 = fma(wv, (double)d[r + 1][c],     dd10);
                        dd11 = fma(wv, (double)d[r + 1][c + 1], dd11);
                    }
                double mxd = fmax(fmax(dd00, dd01), fmax(dd10, dd11));
                rv = (float)rint(fmin(fmax(0.5 * mxd, 0.0), 3.0));
            }
            int lv = (int)rv;
            int v = lv | (__shfl_xor(lv, 1, 64) << 8);
            v |= (__shfl_xor(v, 2, 64) << 16);
            if ((lane & 3) == 0)
                p1i[(i + 1) * P_P1 + (j + 1)] = v;
        }
    }
    LDS_FENCE();

    // ---- phase 2: conv2 via sdot4 with ternary skip; result stays in register ----
    int h4 = 0;                                        // packed 4 oc levels for pix=lane
    if (act && lane < 49) {
        const int i = lane / 7, j = lane - 7 * i;
        const int* bp = p1i + (2 * i) * P_P1 + 2 * j;
        int d[4][4];
        #pragma unroll
        for (int r = 0; r < 4; ++r) {
            int2 a = *(const int2*)(bp + r * P_P1);
            int2 b = *(const int2*)(bp + r * P_P1 + 2);
            d[r][0] = a.x; d[r][1] = a.y; d[r][2] = b.x; d[r][3] = b.y;
        }
        const int L1 = wsi[WSI_L1], L3 = wsi[WSI_L3], L5 = wsi[WSI_L5];
        #pragma unroll
        for (int oc = 0; oc < 4; ++oc) {
            int a00 = 0, a01 = 0, a10 = 0, a11 = 0;
            #pragma unroll
            for (int r = 0; r < 3; ++r)
                #pragma unroll
                for (int c = 0; c < 3; ++c) {
                    int wv = wsi[WSI_W2P + oc * 9 + r * 3 + c];  // uniform -> SGPR
                    if (wv != 0) {                     // uniform skip: no-op if kept
                        a00 = dot4(d[r][c],         wv, a00);
                        a01 = dot4(d[r][c + 1],     wv, a01);
                        a10 = dot4(d[r + 1][c],     wv, a10);
                        a11 = dot4(d[r + 1][c + 1], wv, a11);
                    }
                }
            int mx = max(max(a00, a01), max(a10, a11));
            int lv = (mx >= L1) + (mx >= L3) + (mx >= L5);
            h4 |= lv << (8 * oc);
        }
    }

    // ---- phase 3: FC via sdot4 + packed-int16 butterfly (h4 passed in register) ----
    if (act) {
        const int* wr = wsi + WSI_WFP + min(lane, 48) * 12;  // clamped: h4=0 for lane>=49
        int4 wa = *(const int4*)wr;
        int4 wb = *(const int4*)(wr + 4);
        int2 wc = *(const int2*)(wr + 8);
        int a0 = dot4(h4, wa.x, 0), a1 = dot4(h4, wa.y, 0);
        int a2 = dot4(h4, wa.z, 0), a3 = dot4(h4, wa.w, 0);
        int a4 = dot4(h4, wb.x, 0), a5 = dot4(h4, wb.y, 0);
        int a6 = dot4(h4, wb.z, 0), a7 = dot4(h4, wb.w, 0);
        int a8 = dot4(h4, wc.x, 0), a9 = dot4(h4, wc.y, 0);
        int p[5];
        p[0] = (a0 << 16) | (a1 & 0xFFFF);
        p[1] = (a2 << 16) | (a3 & 0xFFFF);
        p[2] = (a4 << 16) | (a5 & 0xFFFF);
        p[3] = (a6 << 16) | (a7 & 0xFFFF);
        p[4] = (a8 << 16) | (a9 & 0xFFFF);
        #pragma unroll
        for (int off = 32; off; off >>= 1) {
            #pragma unroll
            for (int k = 0; k < 5; ++k)
                p[k] = pk_add16(p[k], __shfl_xor(p[k], off, 64));
        }
        if (lane == 0) {
            const float sf2 = wsf[WSF_SF2];
            float2* op = (float2*)(out + (size_t)img * 10);
            #pragma unroll
            for (int k = 0; k < 5; ++k) {
                int hi = p[k] >> 16;
                int lo = (int)(short)(p[k] & 0xFFFF);
                op[k] = make_float2(sf2 * (float)hi, sf2 * (float)lo);
            }
        }
    }
}

extern "C" void kernel_launch(void* const* d_in, const int* in_sizes, int n_in,
                              void* d_out, int out_size, void* d_ws, size_t ws_size,
                              hipStream_t stream) {
    const float* x  = (const float*)d_in[0];
    const float* w1 = (const float*)d_in[1];
    const float* w2 = (const float*)d_in[2];
    const float* wf = (const float*)d_in[3];
    float* wsf = (float*)d_ws;
    float* out = (float*)d_out;

    const int B = in_sizes[0] / 784;

    qweights_kernel<<<1, 256, 0, stream>>>(w1, w2, wf, wsf);
    fused_net_kernel<<<(B + WAVES - 1) / WAVES, 256, 0, stream>>>(x, wsf, out, B);
}

// Round 9
// 183.988 us; speedup vs baseline: 1.0483x; 1.0483x over previous
//
#include <hip/hip_runtime.h>

// Workspace layout: float region + int region (ints start at (int*)wsf + 64)
#define WSF_W1Q  0      // 36 floats: s1*lvl (exact)
#define WSF_SF2  36     // 2*sf
#define WSI_W2P  0      // 36 ints: conv2 packed ternary i8x4 (ic in bytes), [oc][tap]
#define WSI_L1   36     // conv2 integer thresholds on L = sum(lvl_in * w), lvl in {0..3}
#define WSI_L3   37
#define WSI_L5   38
#define WSI_WFP  40     // 49*12 ints: FC packed ternary i8x4, [pix][o] pitch 12; byte b = wf[o][b*49+pix]

#define TOL2 4e-5f      // rescue band half-width in f-units (f = mx/2)

typedef float v2f __attribute__((ext_vector_type(2)));

__device__ __forceinline__ int dot4(int a, int b, int c) {
    return __builtin_amdgcn_sdot4(a, b, c, false);
}
__device__ __forceinline__ int pk_add16(int a, int b) {
    int r;
    asm("v_pk_add_i16 %0, %1, %2" : "=v"(r) : "v"(a), "v"(b));
    return r;
}
// packed 2xfp32 FMA, weight pair in SGPRs (uniform): src0 is the 1 allowed SGPR
__device__ __forceinline__ v2f pk_fma_sv(v2f ws, v2f d, v2f acc) {
    v2f r;
    asm("v_pk_fma_f32 %0, %1, %2, %3" : "=v"(r) : "s"(ws), "v"(d), "v"(acc));
    return r;
}

// wave-local LDS drain (no cross-wave rendezvous needed: zero inter-wave sharing)
#define LDS_FENCE() asm volatile("s_waitcnt lgkmcnt(0)" ::: "memory")

// ---------------------------------------------------------------------------
// Pre-kernel: 2-bit weight quant (fp64 decisions) + integer packing. 256 thr.
// ---------------------------------------------------------------------------
__global__ void qweights_kernel(const float* __restrict__ w1,
                                const float* __restrict__ w2,
                                const float* __restrict__ wf,
                                float* __restrict__ wsf) {
    int* wsi = (int*)wsf + 64;
    __shared__ float red[256];
    const int tid = threadIdx.x;

    float m = 0.f;
    if (tid < 36) m = fabsf(w1[tid]);
    red[tid] = m; __syncthreads();
    for (int s = 128; s > 0; s >>= 1) { if (tid < s) red[tid] = fmaxf(red[tid], red[tid + s]); __syncthreads(); }
    const float s1 = red[0]; __syncthreads();

    m = 0.f;
    if (tid < 144) m = fabsf(w2[tid]);
    red[tid] = m; __syncthreads();
    for (int s = 128; s > 0; s >>= 1) { if (tid < s) red[tid] = fmaxf(red[tid], red[tid + s]); __syncthreads(); }
    const float s2 = red[0]; __syncthreads();

    m = 0.f;
    for (int i = tid; i < 1960; i += 256) m = fmaxf(m, fabsf(wf[i]));
    red[tid] = m; __syncthreads();
    for (int s = 128; s > 0; s >>= 1) { if (tid < s) red[tid] = fmaxf(red[tid], red[tid + s]); __syncthreads(); }
    const float sf = red[0];

    if (tid < 36) {
        double l = rint((double)w1[tid] / (double)s1);
        l = fmin(fmax(l, -1.0), 1.0);
        wsf[WSF_W1Q + tid] = (float)(l * (double)s1);
    }
    if (tid >= 64 && tid < 100) {
        int u = tid - 64;
        int oc = u / 9, tap = u % 9;
        int dy = tap / 3, dx = tap % 3;
        int v = 0;
        for (int ic = 0; ic < 4; ++ic) {
            double l = rint((double)w2[((oc * 4 + ic) * 3 + dy) * 3 + dx] / (double)s2);
            l = fmin(fmax(l, -1.0), 1.0);
            v |= ((int)l & 0xFF) << (8 * ic);
        }
        wsi[WSI_W2P + u] = v;
    }
    // FC pack [pix][o]: byte b = lvl(wf[o*196 + b*49 + pix]) -- matches h4 packing
    for (int u = tid; u < 49 * 12; u += 256) {
        int pix = u / 12, o = u - 12 * pix;
        int v = 0;
        if (o < 10) {
            for (int b = 0; b < 4; ++b) {
                double l = rint((double)wf[o * 196 + b * 49 + pix] / (double)sf);
                l = fmin(fmax(l, -1.0), 1.0);
                v |= ((int)l & 0xFF) << (8 * b);
            }
        }
        wsi[WSI_WFP + u] = v;
    }
    // conv2 thresholds via wave-0 ballot: pre-act = 2*s2*L, L in [0,108]
    if (tid < 64) {
        const int lane = tid;
        double xa = 2.0 * (double)s2 * (double)lane;
        double xb = 2.0 * (double)s2 * (double)(lane + 64);
        double la = rint(fmin(fmax(xa, 0.0), 6.0) * 0.5);
        double lb = rint(fmin(fmax(xb, 0.0), 6.0) * 0.5);
        unsigned long long b1a = __ballot(la >= 1.0), b1b = __ballot(lb >= 1.0);
        unsigned long long b3a = __ballot(la >= 2.0), b3b = __ballot(lb >= 2.0);
        unsigned long long b5a = __ballot(la >= 3.0), b5b = __ballot(lb >= 3.0);
        if (lane == 0) {
            int L1 = b1a ? __ffsll(b1a) - 1 : (b1b ? 64 + __ffsll(b1b) - 1 : 4096);
            int L3 = b3a ? __ffsll(b3a) - 1 : (b3b ? 64 + __ffsll(b3b) - 1 : 4096);
            int L5 = b5a ? __ffsll(b5a) - 1 : (b5b ? 64 + __ffsll(b5b) - 1 : 4096);
            wsi[WSI_L1] = L1; wsi[WSI_L3] = L3; wsi[WSI_L5] = L5;
            wsf[WSF_SF2] = 2.0f * sf;
        }
    }
}

// ---------------------------------------------------------------------------
// Fused net: one wave per image, 4 waves/block, no __syncthreads.
// R9 = R7 structure (rolled phase-1 loop, branch-free inner loops — R8's
// unroll+skip-branches spilled to scratch: WRITE_SIZE 1.3->41.6 MB) with
// the one safe R8 change kept: conv2 result h4 stays in register for FC.
// ---------------------------------------------------------------------------
#define WAVES 4
#define P_IN 30
#define P_P1 18

__global__ __launch_bounds__(256, 8)
void fused_net_kernel(const float* __restrict__ x,
                      const float* __restrict__ wsf,
                      float* __restrict__ out, int B) {
    const int* wsi = (const int*)wsf + 64;

    __shared__ __align__(16) float s_in[WAVES][900];        // 30x30 padded
    __shared__ __align__(16) int   s_p1[WAVES][16 * P_P1];  // packed lvl{0..3} x4 ic

    const int tid  = threadIdx.x;
    const int wave = tid >> 6;
    const int lane = tid & 63;
    const int img  = blockIdx.x * WAVES + wave;
    const bool act = (img < B);

    float* in_p = s_in[wave];
    int*   p1i  = s_p1[wave];
    const float* w1 = wsf + WSF_W1Q;

    // ---- phase 0a: zero exactly the READ-SET border frames ----
    if (lane < 30) { in_p[lane] = 0.f; in_p[29 * 30 + lane] = 0.f; }
    if (lane < 28) { in_p[(lane + 1) * 30] = 0.f; in_p[(lane + 1) * 30 + 29] = 0.f; }
    // p1i read set rows 0..15 x cols 0..15; interior rows/cols 1..14 written.
    if (lane < 60) {
        int bi;
        if (lane < 16)      bi = lane;                       // row 0, cols 0..15
        else if (lane < 32) bi = 15 * P_P1 + (lane - 16);    // row 15, cols 0..15
        else if (lane < 46) bi = (lane - 31) * P_P1;         // rows 1..14, col 0
        else                bi = (lane - 45) * P_P1 + 15;    // rows 1..14, col 15
        p1i[bi] = 0;
    }

    // ---- phase 0b: load 28x28 input into padded interior ----
    if (act) {
        const float4* xv = (const float4*)(x + (size_t)img * 784);
        for (int t = lane; t < 196; t += 64) {
            float4 v = xv[t];
            int row = t / 7;
            int c   = (t - row * 7) * 4;
            float* dst = in_p + (row + 1) * P_IN + c + 1;
            dst[0] = v.x; dst[1] = v.y; dst[2] = v.z; dst[3] = v.w;
        }
    }
    LDS_FENCE();

    // ---- phase 1: conv1 via v_pk_fma_f32 (+fp64 rescue) + pool-then-quant ----
    if (act) {
        #pragma unroll 1
        for (int it = 0; it < 3; ++it) {
            const int t = lane + (it << 6);            // < 192
            const int i = t / 14, j = t - i * 14;
            const float* base = in_p + (2 * i) * P_IN + 2 * j;
            v2f A[4], S[4], Bp[4];                      // cols {0,1},{1,2},{2,3}
            #pragma unroll
            for (int r = 0; r < 4; ++r) {
                const float* rp = base + r * P_IN;
                A[r]  = *(const v2f*)rp;
                Bp[r] = *(const v2f*)(rp + 2);
                v2f s; s.x = rp[1]; s.y = rp[2];
                S[r] = s;
            }
            float rr[4];
            float dmax = 0.f;
            #pragma unroll
            for (int oc = 0; oc < 4; ++oc) {
                const float* w9 = w1 + oc * 9;
                v2f acc01 = {0.f, 0.f}, acc23 = {0.f, 0.f};
                #pragma unroll
                for (int r = 0; r < 3; ++r) {
                    float wa = w9[r * 3], wb = w9[r * 3 + 1], wc = w9[r * 3 + 2];
                    v2f wav = {wa, wa}, wbv = {wb, wb}, wcv = {wc, wc};
                    acc01 = pk_fma_sv(wav, A[r],      acc01);
                    acc01 = pk_fma_sv(wbv, S[r],      acc01);
                    acc01 = pk_fma_sv(wcv, Bp[r],     acc01);
                    acc23 = pk_fma_sv(wav, A[r + 1],  acc23);
                    acc23 = pk_fma_sv(wbv, S[r + 1],  acc23);
                    acc23 = pk_fma_sv(wcv, Bp[r + 1], acc23);
                }
                float mx = fmaxf(fmaxf(acc01.x, acc01.y), fmaxf(acc23.x, acc23.y));
                float cc = fminf(fmaxf(0.5f * mx, 0.f), 3.f);
                float rv = rintf(cc);
                rr[oc] = rv;
                dmax = fmaxf(dmax, fabsf(cc - rv));
            }
            if (dmax > 0.5f - TOL2) {                  // rare fp64 rescue
                double dd[4][4];
                #pragma unroll
                for (int r = 0; r < 4; ++r) {
                    dd[r][0] = (double)A[r].x; dd[r][1] = (double)A[r].y;
                    dd[r][2] = (double)Bp[r].x; dd[r][3] = (double)Bp[r].y;
                }
                #pragma unroll
                for (int oc = 0; oc < 4; ++oc) {
                    double a00 = 0, a01 = 0, a10 = 0, a11 = 0;
                    #pragma unroll
                    for (int r = 0; r < 3; ++r)
                        #pragma unroll
                        for (int c = 0; c < 3; ++c) {
                            double wv = (double)w1[oc * 9 + r * 3 + c];
                            a00 = fma(wv, dd[r][c],         a00);
                            a01 = fma(wv, dd[r][c + 1],     a01);
                            a10 = fma(wv, dd[r + 1][c],     a10);
                            a11 = fma(wv, dd[r + 1][c + 1], a11);
                        }
                    double mx = fmax(fmax(a00, a01), fmax(a10, a11));
                    rr[oc] = (float)rint(fmin(fmax(0.5 * mx, 0.0), 3.0));
                }
            }
            p1i[(i + 1) * P_P1 + (j + 1)] =
                (int)rr[0] | ((int)rr[1] << 8) | ((int)rr[2] << 16) | ((int)rr[3] << 24);
        }
        // tail: pixels 192..195, oc-split over lanes 0..15
        if (lane < 16) {
            const int px = 192 + (lane >> 2), oc = lane & 3;
            const int i = 13, j = px - 182;            // j in 10..13
            const float* base = in_p + (2 * i) * P_IN + 2 * j;
            float d[4][4];
            #pragma unroll
            for (int r = 0; r < 4; ++r) {
                float2 a = *(const float2*)(base + r * P_IN);
                float2 b = *(const float2*)(base + r * P_IN + 2);
                d[r][0] = a.x; d[r][1] = a.y; d[r][2] = b.x; d[r][3] = b.y;
            }
            const float* w9 = w1 + oc * 9;
            float a00 = 0.f, a01 = 0.f, a10 = 0.f, a11 = 0.f;
            #pragma unroll
            for (int r = 0; r < 3; ++r)
                #pragma unroll
                for (int c = 0; c < 3; ++c) {
                    float wv = w9[r * 3 + c];
                    a00 = fmaf(wv, d[r][c],         a00);
                    a01 = fmaf(wv, d[r][c + 1],     a01);
                    a10 = fmaf(wv, d[r + 1][c],     a10);
                    a11 = fmaf(wv, d[r + 1][c + 1], a11);
                }
            float mx = fmaxf(fmaxf(a00, a01), fmaxf(a10, a11));
            float cc = fminf(fmaxf(0.5f * mx, 0.f), 3.f);
            float rv = rintf(cc);
            if (fabsf(cc - rv) > 0.5f - TOL2) {
                double dd00 = 0, dd01 = 0, dd10 = 0, dd11 = 0;
                #pragma unroll
                for (int r = 0; r < 3; ++r)
                    #pragma unroll
                    for (int c = 0; c < 3; ++c) {
                        double wv = (double)w9[r * 3 + c];
                        dd00 = fma(wv, (double)d[r][c],         dd00);
                        dd01 = fma(wv, (double)d[r][c + 1],     dd01);
                        dd10 = fma(wv, (double)d[r + 1][c],     dd10);
                        dd11 = fma(wv, (double)d[r + 1][c + 1], dd11);
                    }
                double mxd = fmax(fmax(dd00, dd01), fmax(dd10, dd11));
                rv = (float)rint(fmin(fmax(0.5 * mxd, 0.0), 3.0));
            }
            int lv = (int)rv;
            int v = lv | (__shfl_xor(lv, 1, 64) << 8);
            v |= (__shfl_xor(v, 2, 64) << 16);
            if ((lane & 3) == 0)
                p1i[(i + 1) * P_P1 + (j + 1)] = v;
        }
    }
    LDS_FENCE();

    // ---- phase 2: conv2 via sdot4; result stays in register for FC ----
    int h4 = 0;                                        // packed 4 oc levels, pix=lane
    if (act && lane < 49) {
        const int i = lane / 7, j = lane - 7 * i;
        const int* bp = p1i + (2 * i) * P_P1 + 2 * j;
        int d[4][4];
        #pragma unroll
        for (int r = 0; r < 4; ++r) {
            int2 a = *(const int2*)(bp + r * P_P1);
            int2 b = *(const int2*)(bp + r * P_P1 + 2);
            d[r][0] = a.x; d[r][1] = a.y; d[r][2] = b.x; d[r][3] = b.y;
        }
        const int L1 = wsi[WSI_L1], L3 = wsi[WSI_L3], L5 = wsi[WSI_L5];
        #pragma unroll
        for (int oc = 0; oc < 4; ++oc) {
            int a00 = 0, a01 = 0, a10 = 0, a11 = 0;
            #pragma unroll
            for (int r = 0; r < 3; ++r)
                #pragma unroll
                for (int c = 0; c < 3; ++c) {
                    int wv = wsi[WSI_W2P + oc * 9 + r * 3 + c];  // uniform -> SGPR
                    a00 = dot4(d[r][c],         wv, a00);
                    a01 = dot4(d[r][c + 1],     wv, a01);
                    a10 = dot4(d[r + 1][c],     wv, a10);
                    a11 = dot4(d[r + 1][c + 1], wv, a11);
                }
            int mx = max(max(a00, a01), max(a10, a11));
            int lv = (mx >= L1) + (mx >= L3) + (mx >= L5);
            h4 |= lv << (8 * oc);
        }
    }

    // ---- phase 3: FC via sdot4 + packed-int16 butterfly (h4 in register) ----
    if (act) {
        const int* wr = wsi + WSI_WFP + min(lane, 48) * 12;  // clamped: h4=0 for lane>=49
        int4 wa = *(const int4*)wr;
        int4 wb = *(const int4*)(wr + 4);
        int2 wc = *(const int2*)(wr + 8);
        int a0 = dot4(h4, wa.x, 0), a1 = dot4(h4, wa.y, 0);
        int a2 = dot4(h4, wa.z, 0), a3 = dot4(h4, wa.w, 0);
        int a4 = dot4(h4, wb.x, 0), a5 = dot4(h4, wb.y, 0);
        int a6 = dot4(h4, wb.z, 0), a7 = dot4(h4, wb.w, 0);
        int a8 = dot4(h4, wc.x, 0), a9 = dot4(h4, wc.y, 0);
        int p[5];
        p[0] = (a0 << 16) | (a1 & 0xFFFF);
        p[1] = (a2 << 16) | (a3 & 0xFFFF);
        p[2] = (a4 << 16) | (a5 & 0xFFFF);
        p[3] = (a6 << 16) | (a7 & 0xFFFF);
        p[4] = (a8 << 16) | (a9 & 0xFFFF);
        #pragma unroll
        for (int off = 32; off; off >>= 1) {
            #pragma unroll
            for (int k = 0; k < 5; ++k)
                p[k] = pk_add16(p[k], __shfl_xor(p[k], off, 64));
        }
        if (lane == 0) {
            const float sf2 = wsf[WSF_SF2];
            float2* op = (float2*)(out + (size_t)img * 10);
            #pragma unroll
            for (int k = 0; k < 5; ++k) {
                int hi = p[k] >> 16;
                int lo = (int)(short)(p[k] & 0xFFFF);
                op[k] = make_float2(sf2 * (float)hi, sf2 * (float)lo);
            }
        }
    }
}

extern "C" void kernel_launch(void* const* d_in, const int* in_sizes, int n_in,
                              void* d_out, int out_size, void* d_ws, size_t ws_size,
                              hipStream_t stream) {
    const float* x  = (const float*)d_in[0];
    const float* w1 = (const float*)d_in[1];
    const float* w2 = (const float*)d_in[2];
    const float* wf = (const float*)d_in[3];
    float* wsf = (float*)d_ws;
    float* out = (float*)d_out;

    const int B = in_sizes[0] / 784;

    qweights_kernel<<<1, 256, 0, stream>>>(w1, w2, wf, wsf);
    fused_net_kernel<<<(B + WAVES - 1) / WAVES, 256, 0, stream>>>(x, wsf, out, B);
}

// Round 10
// 180.359 us; speedup vs baseline: 1.0694x; 1.0201x over previous
//
#include <hip/hip_runtime.h>

// Workspace layout: float region + int region (ints start at (int*)wsf + 64)
#define WSF_W1Q  0      // 36 floats: s1*lvl (exact)
#define WSF_SF2  36     // 2*sf
#define WSI_W2P  0      // 36 ints: conv2 packed ternary i8x4 (ic in bytes), [oc][tap]
#define WSI_L1   36     // conv2 integer thresholds on L = sum(lvl_in * w), lvl in {0..3}
#define WSI_L3   37
#define WSI_L5   38
#define WSI_WFP  40     // 49*12 ints: FC packed ternary i8x4, [pix][o] pitch 12; byte b = wf[o][b*49+pix]

#define TOL2 4e-5f      // rescue band half-width in f-units (f = mx/2)

typedef float v2f __attribute__((ext_vector_type(2)));

__device__ __forceinline__ int dot4(int a, int b, int c) {
    return __builtin_amdgcn_sdot4(a, b, c, false);
}
__device__ __forceinline__ int pk_add16(int a, int b) {
    int r;
    asm("v_pk_add_i16 %0, %1, %2" : "=v"(r) : "v"(a), "v"(b));
    return r;
}
// packed 2xfp32 FMA, weight pair in SGPRs (uniform): src0 is the 1 allowed SGPR
__device__ __forceinline__ v2f pk_fma_sv(v2f ws, v2f d, v2f acc) {
    v2f r;
    asm("v_pk_fma_f32 %0, %1, %2, %3" : "=v"(r) : "s"(ws), "v"(d), "v"(acc));
    return r;
}

// wave-local LDS drain (no cross-wave rendezvous needed: zero inter-wave sharing)
#define LDS_FENCE() asm volatile("s_waitcnt lgkmcnt(0)" ::: "memory")

// ---------------------------------------------------------------------------
// Pre-kernel: 2-bit weight quant (fp64 decisions) + integer packing. 256 thr.
// ---------------------------------------------------------------------------
__global__ void qweights_kernel(const float* __restrict__ w1,
                                const float* __restrict__ w2,
                                const float* __restrict__ wf,
                                float* __restrict__ wsf) {
    int* wsi = (int*)wsf + 64;
    __shared__ float red[256];
    const int tid = threadIdx.x;

    float m = 0.f;
    if (tid < 36) m = fabsf(w1[tid]);
    red[tid] = m; __syncthreads();
    for (int s = 128; s > 0; s >>= 1) { if (tid < s) red[tid] = fmaxf(red[tid], red[tid + s]); __syncthreads(); }
    const float s1 = red[0]; __syncthreads();

    m = 0.f;
    if (tid < 144) m = fabsf(w2[tid]);
    red[tid] = m; __syncthreads();
    for (int s = 128; s > 0; s >>= 1) { if (tid < s) red[tid] = fmaxf(red[tid], red[tid + s]); __syncthreads(); }
    const float s2 = red[0]; __syncthreads();

    m = 0.f;
    for (int i = tid; i < 1960; i += 256) m = fmaxf(m, fabsf(wf[i]));
    red[tid] = m; __syncthreads();
    for (int s = 128; s > 0; s >>= 1) { if (tid < s) red[tid] = fmaxf(red[tid], red[tid + s]); __syncthreads(); }
    const float sf = red[0];

    if (tid < 36) {
        double l = rint((double)w1[tid] / (double)s1);
        l = fmin(fmax(l, -1.0), 1.0);
        wsf[WSF_W1Q + tid] = (float)(l * (double)s1);
    }
    if (tid >= 64 && tid < 100) {
        int u = tid - 64;
        int oc = u / 9, tap = u % 9;
        int dy = tap / 3, dx = tap % 3;
        int v = 0;
        for (int ic = 0; ic < 4; ++ic) {
            double l = rint((double)w2[((oc * 4 + ic) * 3 + dy) * 3 + dx] / (double)s2);
            l = fmin(fmax(l, -1.0), 1.0);
            v |= ((int)l & 0xFF) << (8 * ic);
        }
        wsi[WSI_W2P + u] = v;
    }
    // FC pack [pix][o]: byte b = lvl(wf[o*196 + b*49 + pix]) -- matches h4 packing
    for (int u = tid; u < 49 * 12; u += 256) {
        int pix = u / 12, o = u - 12 * pix;
        int v = 0;
        if (o < 10) {
            for (int b = 0; b < 4; ++b) {
                double l = rint((double)wf[o * 196 + b * 49 + pix] / (double)sf);
                l = fmin(fmax(l, -1.0), 1.0);
                v |= ((int)l & 0xFF) << (8 * b);
            }
        }
        wsi[WSI_WFP + u] = v;
    }
    // conv2 thresholds via wave-0 ballot: pre-act = 2*s2*L, L in [0,108]
    if (tid < 64) {
        const int lane = tid;
        double xa = 2.0 * (double)s2 * (double)lane;
        double xb = 2.0 * (double)s2 * (double)(lane + 64);
        double la = rint(fmin(fmax(xa, 0.0), 6.0) * 0.5);
        double lb = rint(fmin(fmax(xb, 0.0), 6.0) * 0.5);
        unsigned long long b1a = __ballot(la >= 1.0), b1b = __ballot(lb >= 1.0);
        unsigned long long b3a = __ballot(la >= 2.0), b3b = __ballot(lb >= 2.0);
        unsigned long long b5a = __ballot(la >= 3.0), b5b = __ballot(lb >= 3.0);
        if (lane == 0) {
            int L1 = b1a ? __ffsll(b1a) - 1 : (b1b ? 64 + __ffsll(b1b) - 1 : 4096);
            int L3 = b3a ? __ffsll(b3a) - 1 : (b3b ? 64 + __ffsll(b3b) - 1 : 4096);
            int L5 = b5a ? __ffsll(b5a) - 1 : (b5b ? 64 + __ffsll(b5b) - 1 : 4096);
            wsi[WSI_L1] = L1; wsi[WSI_L3] = L3; wsi[WSI_L5] = L5;
            wsf[WSF_SF2] = 2.0f * sf;
        }
    }
}

// ---------------------------------------------------------------------------
// Fused net: one wave per image, 4 waves/block, no __syncthreads.
// R10 = R9 + (a) manual hoist of uniform weight/threshold loads past the
// asm "memory" fences (which otherwise pin them after each phase boundary),
// (b) S-pair composed from registers instead of re-read from LDS,
// (c) v_med3_f32 clamp. Numerically bit-identical to R9/R7.
// ---------------------------------------------------------------------------
#define WAVES 4
#define P_IN 30
#define P_P1 18

__global__ __launch_bounds__(256, 8)
void fused_net_kernel(const float* __restrict__ x,
                      const float* __restrict__ wsf,
                      float* __restrict__ out, int B) {
    const int* wsi = (const int*)wsf + 64;

    __shared__ __align__(16) float s_in[WAVES][900];        // 30x30 padded
    __shared__ __align__(16) int   s_p1[WAVES][16 * P_P1];  // packed lvl{0..3} x4 ic

    const int tid  = threadIdx.x;
    const int wave = tid >> 6;
    const int lane = tid & 63;
    const int img  = blockIdx.x * WAVES + wave;
    const bool act = (img < B);

    float* in_p = s_in[wave];
    int*   p1i  = s_p1[wave];
    const float* w1 = wsf + WSF_W1Q;

    // ---- hoisted uniform loads (issue before any LDS op / fence) ----
    int w2r[36];                                   // conv2 packed weights -> SGPRs
    #pragma unroll
    for (int u = 0; u < 36; ++u) w2r[u] = wsi[WSI_W2P + u];
    const int L1 = wsi[WSI_L1], L3 = wsi[WSI_L3], L5 = wsi[WSI_L5];

    // ---- input prefetch (global loads issued before LDS writes) ----
    float4 i0, i1, i2, i3;
    if (act) {
        const float4* xv = (const float4*)(x + (size_t)img * 784);
        i0 = xv[lane];
        i1 = xv[lane + 64];
        i2 = xv[lane + 128];
        if (lane < 4) i3 = xv[192 + lane];
    }

    // ---- phase 0a: zero exactly the READ-SET border frames ----
    if (lane < 30) { in_p[lane] = 0.f; in_p[29 * 30 + lane] = 0.f; }
    if (lane < 28) { in_p[(lane + 1) * 30] = 0.f; in_p[(lane + 1) * 30 + 29] = 0.f; }
    // p1i read set rows 0..15 x cols 0..15; interior rows/cols 1..14 written.
    if (lane < 60) {
        int bi;
        if (lane < 16)      bi = lane;                       // row 0, cols 0..15
        else if (lane < 32) bi = 15 * P_P1 + (lane - 16);    // row 15, cols 0..15
        else if (lane < 46) bi = (lane - 31) * P_P1;         // rows 1..14, col 0
        else                bi = (lane - 45) * P_P1 + 15;    // rows 1..14, col 15
        p1i[bi] = 0;
    }

    // ---- phase 0b: store prefetched input into padded interior ----
    if (act) {
        #pragma unroll
        for (int q = 0; q < 4; ++q) {
            int t = lane + (q << 6);
            if (q == 3) t = 192 + lane;
            float4 v = (q == 0) ? i0 : (q == 1) ? i1 : (q == 2) ? i2 : i3;
            if (q < 3 || lane < 4) {
                int row = t / 7;
                int c   = (t - row * 7) * 4;
                float* dst = in_p + (row + 1) * P_IN + c + 1;
                dst[0] = v.x; dst[1] = v.y; dst[2] = v.z; dst[3] = v.w;
            }
        }
    }
    LDS_FENCE();

    // ---- phase 1: conv1 via v_pk_fma_f32 (+fp64 rescue) + pool-then-quant ----
    if (act) {
        #pragma unroll 1
        for (int it = 0; it < 3; ++it) {
            const int t = lane + (it << 6);            // < 192
            const int i = t / 14, j = t - i * 14;
            const float* base = in_p + (2 * i) * P_IN + 2 * j;
            v2f A[4], S[4], Bp[4];                      // cols {0,1},{1,2},{2,3}
            #pragma unroll
            for (int r = 0; r < 4; ++r) {
                const float* rp = base + r * P_IN;
                A[r]  = *(const v2f*)rp;
                Bp[r] = *(const v2f*)(rp + 2);
                v2f s; s.x = A[r].y; s.y = Bp[r].x;     // from registers, no LDS re-read
                S[r] = s;
            }
            float rr[4];
            float dmax = 0.f;
            #pragma unroll
            for (int oc = 0; oc < 4; ++oc) {
                const float* w9 = w1 + oc * 9;
                v2f acc01 = {0.f, 0.f}, acc23 = {0.f, 0.f};
                #pragma unroll
                for (int r = 0; r < 3; ++r) {
                    float wa = w9[r * 3], wb = w9[r * 3 + 1], wc = w9[r * 3 + 2];
                    v2f wav = {wa, wa}, wbv = {wb, wb}, wcv = {wc, wc};
                    acc01 = pk_fma_sv(wav, A[r],      acc01);
                    acc01 = pk_fma_sv(wbv, S[r],      acc01);
                    acc01 = pk_fma_sv(wcv, Bp[r],     acc01);
                    acc23 = pk_fma_sv(wav, A[r + 1],  acc23);
                    acc23 = pk_fma_sv(wbv, S[r + 1],  acc23);
                    acc23 = pk_fma_sv(wcv, Bp[r + 1], acc23);
                }
                float mx = fmaxf(fmaxf(acc01.x, acc01.y), fmaxf(acc23.x, acc23.y));
                float cc = __builtin_amdgcn_fmed3f(0.5f * mx, 0.f, 3.f);
                float rv = rintf(cc);
                rr[oc] = rv;
                dmax = fmaxf(dmax, fabsf(cc - rv));
            }
            if (dmax > 0.5f - TOL2) {                  // rare fp64 rescue
                double dd[4][4];
                #pragma unroll
                for (int r = 0; r < 4; ++r) {
                    dd[r][0] = (double)A[r].x; dd[r][1] = (double)A[r].y;
                    dd[r][2] = (double)Bp[r].x; dd[r][3] = (double)Bp[r].y;
                }
                #pragma unroll
                for (int oc = 0; oc < 4; ++oc) {
                    double a00 = 0, a01 = 0, a10 = 0, a11 = 0;
                    #pragma unroll
                    for (int r = 0; r < 3; ++r)
                        #pragma unroll
                        for (int c = 0; c < 3; ++c) {
                            double wv = (double)w1[oc * 9 + r * 3 + c];
                            a00 = fma(wv, dd[r][c],         a00);
                            a01 = fma(wv, dd[r][c + 1],     a01);
                            a10 = fma(wv, dd[r + 1][c],     a10);
                            a11 = fma(wv, dd[r + 1][c + 1], a11);
                        }
                    double mx = fmax(fmax(a00, a01), fmax(a10, a11));
                    rr[oc] = (float)rint(fmin(fmax(0.5 * mx, 0.0), 3.0));
                }
            }
            p1i[(i + 1) * P_P1 + (j + 1)] =
                (int)rr[0] | ((int)rr[1] << 8) | ((int)rr[2] << 16) | ((int)rr[3] << 24);
        }
        // tail: pixels 192..195, oc-split over lanes 0..15
        if (lane < 16) {
            const int px = 192 + (lane >> 2), oc = lane & 3;
            const int i = 13, j = px - 182;            // j in 10..13
            const float* base = in_p + (2 * i) * P_IN + 2 * j;
            float d[4][4];
            #pragma unroll
            for (int r = 0; r < 4; ++r) {
                float2 a = *(const float2*)(base + r * P_IN);
                float2 b = *(const float2*)(base + r * P_IN + 2);
                d[r][0] = a.x; d[r][1] = a.y; d[r][2] = b.x; d[r][3] = b.y;
            }
            const float* w9 = w1 + oc * 9;
            float a00 = 0.f, a01 = 0.f, a10 = 0.f, a11 = 0.f;
            #pragma unroll
            for (int r = 0; r < 3; ++r)
                #pragma unroll
                for (int c = 0; c < 3; ++c) {
                    float wv = w9[r * 3 + c];
                    a00 = fmaf(wv, d[r][c],         a00);
                    a01 = fmaf(wv, d[r][c + 1],     a01);
                    a10 = fmaf(wv, d[r + 1][c],     a10);
                    a11 = fmaf(wv, d[r + 1][c + 1], a11);
                }
            float mx = fmaxf(fmaxf(a00, a01), fmaxf(a10, a11));
            float cc = __builtin_amdgcn_fmed3f(0.5f * mx, 0.f, 3.f);
            float rv = rintf(cc);
            if (fabsf(cc - rv) > 0.5f - TOL2) {
                double dd00 = 0, dd01 = 0, dd10 = 0, dd11 = 0;
                #pragma unroll
                for (int r = 0; r < 3; ++r)
                    #pragma unroll
                    for (int c = 0; c < 3; ++c) {
                        double wv = (double)w9[r * 3 + c];
                        dd00 = fma(wv, (double)d[r][c],         dd00);
                        dd01 = fma(wv, (double)d[r][c + 1],     dd01);
                        dd10 = fma(wv, (double)d[r + 1][c],     dd10);
                        dd11 = fma(wv, (double)d[r + 1][c + 1], dd11);
                    }
                double mxd = fmax(fmax(dd00, dd01), fmax(dd10, dd11));
                rv = (float)rint(fmin(fmax(0.5 * mxd, 0.0), 3.0));
            }
            int lv = (int)rv;
            int v = lv | (__shfl_xor(lv, 1, 64) << 8);
            v |= (__shfl_xor(v, 2, 64) << 16);
            if ((lane & 3) == 0)
                p1i[(i + 1) * P_P1 + (j + 1)] = v;
        }
    }
    LDS_FENCE();

    // ---- FC weight prefetch: issue now so latency hides under phase 2 ----
    const int* wr = wsi + WSI_WFP + min(lane, 48) * 12;  // clamped: h4=0 for lane>=49
    int4 wa = *(const int4*)wr;
    int4 wb = *(const int4*)(wr + 4);
    int2 wc = *(const int2*)(wr + 8);

    // ---- phase 2: conv2 via sdot4; result stays in register for FC ----
    int h4 = 0;                                        // packed 4 oc levels, pix=lane
    if (act && lane < 49) {
        const int i = lane / 7, j = lane - 7 * i;
        const int* bp = p1i + (2 * i) * P_P1 + 2 * j;
        int d[4][4];
        #pragma unroll
        for (int r = 0; r < 4; ++r) {
            int2 a = *(const int2*)(bp + r * P_P1);
            int2 b = *(const int2*)(bp + r * P_P1 + 2);
            d[r][0] = a.x; d[r][1] = a.y; d[r][2] = b.x; d[r][3] = b.y;
        }
        #pragma unroll
        for (int oc = 0; oc < 4; ++oc) {
            int a00 = 0, a01 = 0, a10 = 0, a11 = 0;
            #pragma unroll
            for (int r = 0; r < 3; ++r)
                #pragma unroll
                for (int c = 0; c < 3; ++c) {
                    int wv = w2r[oc * 9 + r * 3 + c];   // SGPR, hoisted
                    a00 = dot4(d[r][c],         wv, a00);
                    a01 = dot4(d[r][c + 1],     wv, a01);
                    a10 = dot4(d[r + 1][c],     wv, a10);
                    a11 = dot4(d[r + 1][c + 1], wv, a11);
                }
            int mx = max(max(a00, a01), max(a10, a11));
            int lv = (mx >= L1) + (mx >= L3) + (mx >= L5);
            h4 |= lv << (8 * oc);
        }
    }

    // ---- phase 3: FC via sdot4 + packed-int16 butterfly (h4 in register) ----
    if (act) {
        int a0 = dot4(h4, wa.x, 0), a1 = dot4(h4, wa.y, 0);
        int a2 = dot4(h4, wa.z, 0), a3 = dot4(h4, wa.w, 0);
        int a4 = dot4(h4, wb.x, 0), a5 = dot4(h4, wb.y, 0);
        int a6 = dot4(h4, wb.z, 0), a7 = dot4(h4, wb.w, 0);
        int a8 = dot4(h4, wc.x, 0), a9 = dot4(h4, wc.y, 0);
        int p[5];
        p[0] = (a0 << 16) | (a1 & 0xFFFF);
        p[1] = (a2 << 16) | (a3 & 0xFFFF);
        p[2] = (a4 << 16) | (a5 & 0xFFFF);
        p[3] = (a6 << 16) | (a7 & 0xFFFF);
        p[4] = (a8 << 16) | (a9 & 0xFFFF);
        #pragma unroll
        for (int off = 32; off; off >>= 1) {
            #pragma unroll
            for (int k = 0; k < 5; ++k)
                p[k] = pk_add16(p[k], __shfl_xor(p[k], off, 64));
        }
        if (lane == 0) {
            const float sf2 = wsf[WSF_SF2];
            float2* op = (float2*)(out + (size_t)img * 10);
            #pragma unroll
            for (int k = 0; k < 5; ++k) {
                int hi = p[k] >> 16;
                int lo = (int)(short)(p[k] & 0xFFFF);
                op[k] = make_float2(sf2 * (float)hi, sf2 * (float)lo);
            }
        }
    }
}

extern "C" void kernel_launch(void* const* d_in, const int* in_sizes, int n_in,
                              void* d_out, int out_size, void* d_ws, size_t ws_size,
                              hipStream_t stream) {
    const float* x  = (const float*)d_in[0];
    const float* w1 = (const float*)d_in[1];
    const float* w2 = (const float*)d_in[2];
    const float* wf = (const float*)d_in[3];
    float* wsf = (float*)d_ws;
    float* out = (float*)d_out;

    const int B = in_sizes[0] / 784;

    qweights_kernel<<<1, 256, 0, stream>>>(w1, w2, wf, wsf);
    fused_net_kernel<<<(B + WAVES - 1) / WAVES, 256, 0, stream>>>(x, wsf, out, B);
}